// Round 13
// baseline (144.102 us; speedup 1.0000x reference)
//
#include <hip/hip_runtime.h>
#include <hip/hip_bf16.h>

typedef __attribute__((ext_vector_type(8))) short bf16x8;
typedef __attribute__((ext_vector_type(4))) short s16x4;
typedef __attribute__((ext_vector_type(4))) float f32x4;

#define DIM 512
#define NH 8
#define HD 64
#define SEQ 1024
#define NB 8
#define ROWS (NB*SEQ)

__device__ __forceinline__ short f2bf(float f) {
  union { float f; unsigned u; } v; v.f = f;
  unsigned r = v.u + 0x7fffu + ((v.u >> 16) & 1u);
  return (short)(r >> 16);
}
__device__ __forceinline__ float bf2f(short s) {
  union { unsigned u; float f; } v; v.u = ((unsigned)(unsigned short)s) << 16;
  return v.f;
}
__device__ __forceinline__ f32x4 mfma16(bf16x8 a, bf16x8 b, f32x4 c) {
  return __builtin_amdgcn_mfma_f32_16x16x32_bf16(a, b, c, 0, 0, 0);
}
__device__ __forceinline__ void gload16(const void* g, void* l) {
  __builtin_amdgcn_global_load_lds(
      (const __attribute__((address_space(1))) unsigned int*)g,
      (__attribute__((address_space(3))) unsigned int*)l, 16, 0, 0);
}
// LDS-only barrier: does NOT drain vmcnt.
__device__ __forceinline__ void lds_barrier() {
  __builtin_amdgcn_sched_barrier(0);
  asm volatile("s_waitcnt lgkmcnt(0)" ::: "memory");
  __builtin_amdgcn_s_barrier();
  __builtin_amdgcn_sched_barrier(0);
}

// ------- fused prep: blocks [0,2048) = LayerNorm; [2048,2304) = weight transpose -------
__global__ __launch_bounds__(256) void prep_kernel(
    const float* __restrict__ x, const float* __restrict__ gamma,
    const float* __restrict__ beta, short* __restrict__ xnb,
    const float* __restrict__ Wq, const float* __restrict__ Wk,
    const float* __restrict__ Wv, const float* __restrict__ Wo,
    short* __restrict__ WqkvT, short* __restrict__ WoT) {
  __shared__ float tl[64 * 65];
  const int t = threadIdx.x;
  if (blockIdx.x < 2048) {
    const int row = blockIdx.x * 4 + (t >> 6);
    const int lane = t & 63;
    const float4* xr = reinterpret_cast<const float4*>(x + (size_t)row * DIM);
    const float4 a = xr[lane * 2], b2 = xr[lane * 2 + 1];
    float s = a.x + a.y + a.z + a.w + b2.x + b2.y + b2.z + b2.w;
    float sq = a.x*a.x + a.y*a.y + a.z*a.z + a.w*a.w +
               b2.x*b2.x + b2.y*b2.y + b2.z*b2.z + b2.w*b2.w;
    for (int off = 1; off < 64; off <<= 1) {
      s += __shfl_xor(s, off);
      sq += __shfl_xor(sq, off);
    }
    const float mean = s * (1.0f / DIM);
    const float var = sq * (1.0f / DIM) - mean * mean;
    const float rs = rsqrtf(var + 1e-5f);
    const float4 ga = reinterpret_cast<const float4*>(gamma)[lane * 2];
    const float4 gb = reinterpret_cast<const float4*>(gamma)[lane * 2 + 1];
    const float4 ba = reinterpret_cast<const float4*>(beta)[lane * 2];
    const float4 bb = reinterpret_cast<const float4*>(beta)[lane * 2 + 1];
    union { bf16x8 v; short sh[8]; } o;
    o.sh[0] = f2bf((a.x - mean) * rs * ga.x + ba.x);
    o.sh[1] = f2bf((a.y - mean) * rs * ga.y + ba.y);
    o.sh[2] = f2bf((a.z - mean) * rs * ga.z + ba.z);
    o.sh[3] = f2bf((a.w - mean) * rs * ga.w + ba.w);
    o.sh[4] = f2bf((b2.x - mean) * rs * gb.x + bb.x);
    o.sh[5] = f2bf((b2.y - mean) * rs * gb.y + bb.y);
    o.sh[6] = f2bf((b2.z - mean) * rs * gb.z + bb.z);
    o.sh[7] = f2bf((b2.w - mean) * rs * gb.w + bb.w);
    *reinterpret_cast<bf16x8*>(xnb + (size_t)row * DIM + lane * 8) = o.v;
  } else {
    const int bb = blockIdx.x - 2048;
    const int y = bb >> 6;
    const float* W = (y == 0) ? Wq : (y == 1) ? Wk : (y == 2) ? Wv : Wo;
    const int tile = bb & 63;
    const int k0 = (tile >> 3) * 64, n0 = (tile & 7) * 64;
#pragma unroll
    for (int i = 0; i < 16; ++i) {
      const int idx = i * 256 + t;
      const int k = idx >> 6, n = idx & 63;
      tl[n * 65 + k] = W[(size_t)(k0 + k) * 512 + n0 + n];
    }
    __syncthreads();
#pragma unroll
    for (int i = 0; i < 16; ++i) {
      const int idx = i * 256 + t;
      const int n = idx >> 6, k = idx & 63;
      const short v = f2bf(tl[n * 65 + k]);
      if (y < 3) WqkvT[(size_t)(y * 512 + n0 + n) * 512 + k0 + k] = v;
      else       WoT[(size_t)(n0 + n) * 512 + k0 + k] = v;
    }
  }
}

// ---------------- 128x128 GEMM mainloop, BK=64, 8-seg XOR swizzle ----------------
#define GEMM64_MAIN(A_, BT_, m0_, n0_)                                        \
  f32x4 acc[4][4] = {};                                                       \
  {                                                                           \
    const int srow = 8 * w + (lane >> 3);                                     \
    const int sseg = lane & 7;                                                \
    for (int kb = 0; kb < 512; kb += 64) {                                    \
      __syncthreads();                                                        \
      _Pragma("unroll")                                                       \
      for (int p = 0; p < 4; ++p) {                                           \
        const int r = 32 * p + srow;                                          \
        const int gs = 8 * (sseg ^ (r & 7));                                  \
        gload16(A_ + (size_t)(m0_ + r) * 512 + kb + gs,                       \
                &As[(32 * p + 8 * w) * 64]);                                  \
        gload16(BT_ + (size_t)(n0_ + r) * 512 + kb + gs,                      \
                &Bs[(32 * p + 8 * w) * 64]);                                  \
      }                                                                       \
      __syncthreads();                                                        \
      _Pragma("unroll")                                                       \
      for (int half = 0; half < 2; ++half) {                                  \
        bf16x8 af[4], bfr[4];                                                 \
        _Pragma("unroll")                                                     \
        for (int i = 0; i < 4; ++i) {                                         \
          const int ra = 64 * wr + 16 * i + c16;                              \
          af[i] = *reinterpret_cast<const bf16x8*>(                           \
              &As[ra * 64 + 8 * ((4 * half + g) ^ (ra & 7))]);                \
          const int rb = 64 * wc + 16 * i + c16;                              \
          bfr[i] = *reinterpret_cast<const bf16x8*>(                          \
              &Bs[rb * 64 + 8 * ((4 * half + g) ^ (rb & 7))]);                \
        }                                                                     \
        _Pragma("unroll")                                                     \
        for (int i = 0; i < 4; ++i)                                           \
          _Pragma("unroll")                                                   \
          for (int j = 0; j < 4; ++j)                                         \
            acc[i][j] = mfma16(af[i], bfr[j], acc[i][j]);                     \
      }                                                                       \
    }                                                                         \
  }

// QKV GEMM. V written in MFMA-fragment order MATCHING pa's slot map:
// slot (g,i) <-> k-offset 16*(i>>2) + 4*g + (i&3)
__global__ __launch_bounds__(256) void gemm_qkv(const short* __restrict__ A,
    const short* __restrict__ BT, short* __restrict__ Qo,
    short* __restrict__ Ko, short* __restrict__ VtF) {
  __shared__ short As[128 * 64];
  __shared__ short Bs[128 * 64];
  const int m0 = blockIdx.x * 128, n0 = blockIdx.y * 128;
  const int t = threadIdx.x, w = t >> 6, lane = t & 63, g = lane >> 4, c16 = lane & 15;
  const int wr = w >> 1, wc = w & 1;
  GEMM64_MAIN(A, BT, m0, n0)
  const int z = n0 >> 9;
  const int nl = n0 & 511;
  if (z < 2) {
    short* O = (z == 0) ? Qo : Ko;
#pragma unroll
    for (int i = 0; i < 4; ++i)
#pragma unroll
      for (int j = 0; j < 4; ++j) {
        const int row0 = m0 + 64 * wr + 16 * i + 4 * g;
        const int col = nl + 64 * wc + 16 * j + c16;
#pragma unroll
        for (int e = 0; e < 4; ++e)
          O[(size_t)(row0 + e) * 512 + col] = f2bf(acc[i][j][e]);
      }
  } else {
#pragma unroll
    for (int i = 0; i < 4; ++i)
#pragma unroll
      for (int j = 0; j < 4; ++j) {
        const int row0 = m0 + 64 * wr + 16 * i + 4 * g;   // e=0 base
        const int col = nl + 64 * wc + 16 * j + c16;
        const int bb = row0 >> 10, ss0 = row0 & 1023, hh = col >> 6, dd = col & 63;
        const int cch = ss0 >> 7, kk = ss0 & 127;
        const int w2 = kk >> 5;
        const int g2 = (kk >> 2) & 3;                     // matched slot order
        const int ee0 = 4 * ((kk >> 4) & 1) + (kk & 3);   // ee0 in {0,4}
        const int dt2 = dd >> 4, c162 = dd & 15;
        s16x4 pv;
#pragma unroll
        for (int e = 0; e < 4; ++e) pv[e] = f2bf(acc[i][j][e]);
        *reinterpret_cast<s16x4*>(
            &VtF[((size_t)((((bb * NH + hh) * 8 + cch) * 4 + w2) * 4 + dt2) << 9) +
                 (g2 * 16 + c162) * 8 + ee0]) = pv;
      }
  }
}

__global__ __launch_bounds__(256) void gemm_out(const short* __restrict__ A,
    const short* __restrict__ BT, const short* __restrict__ xnb,
    float* __restrict__ out) {
  __shared__ short As[128 * 64];
  __shared__ short Bs[128 * 64];
  const int m0 = blockIdx.x * 128, n0 = blockIdx.y * 128;
  const int t = threadIdx.x, w = t >> 6, lane = t & 63, g = lane >> 4, c16 = lane & 15;
  const int wr = w >> 1, wc = w & 1;
  GEMM64_MAIN(A, BT, m0, n0)
#pragma unroll
  for (int i = 0; i < 4; ++i)
#pragma unroll
    for (int j = 0; j < 4; ++j)
#pragma unroll
      for (int e = 0; e < 4; ++e) {
        const int row = m0 + 64 * wr + 16 * i + 4 * g + e;
        const int col = n0 + 64 * wc + 16 * j + c16;
        const size_t idx = (size_t)row * 512 + col;
        out[idx] = acc[i][j][e] + bf2f(xnb[idx]);
      }
}

// ------- 4-tile pipelined attn (r9 chunk body, straight-line unrolled tiles) -------
// 64 q-rows/block as tiles 0..3. Tile tau's phase: stores(tau)+PV(tau) || QK^T(tau+1).
// One pacc at a time; per-tile cross-wave reduce rides the next softmax's barriers
// (red2 aliases P32 region, free during softmax). nt stores (r12 A/B: nt wins).
__global__ __launch_bounds__(256, 2) void attn_kernel(
    const short* __restrict__ Qb, const short* __restrict__ Kb,
    const short* __restrict__ VtF, float* __restrict__ attnOut,
    short* __restrict__ Lg) {
  const int bid = blockIdx.x;                 // 1024
  const int rb = (bid >> 3) & 15;             // 64-row block
  const int inst = (bid & 7) * 8 + (bid >> 7);
  const int b = inst >> 3, h = inst & 7;
  const int t = threadIdx.x;
  const int w = t >> 6, lane = t & 63, g = lane >> 4, c16 = lane & 15;
  const int rl = lane >> 3, sgl = lane & 7;
  const int sw = c16 & 7;
  const int rbase = rb * 64;
  const int qrow = t >> 4, qs = t & 15;

  __shared__ __align__(16) char smem[49664];
  __shared__ float red[2][4][16];
  short* Klds = (short*)smem;                  // [2][128*64] = 32 KB
  float* P32a = (float*)(smem + 32768);        // [16][132]
  float* P32b = (float*)(smem + 41216);        // [16][132]

  const short* kgbase = Kb + ((size_t)b * SEQ) * DIM + h * HD;
  const short* vf = VtF + (size_t)inst * 65536;
  const int swz = 8 * (sgl ^ rl);

#define KSTAGE(c_, buf_)                                                       \
  do {                                                                         \
    __builtin_amdgcn_sched_barrier(0);                                         \
    _Pragma("unroll") for (int i_ = 0; i_ < 4; ++i_) {                         \
      gload16(kgbase + (size_t)((c_) * 128 + 32 * w + 8 * i_ + rl) * DIM + swz,\
              &Klds[(buf_) * 8192 + (32 * w + 8 * i_) * 64]);                  \
    }                                                                          \
  } while (0)

  // ---- phase 1: QK^T tile 0 via global_load_lds double-buffer ----
  f32x4 acc[16] = {};
  {
    const short* qp = Qb + ((size_t)(b * SEQ + rbase + c16)) * DIM + h * HD + 8 * g;
    const bf16x8 q0 = *reinterpret_cast<const bf16x8*>(qp);
    const bf16x8 q1 = *reinterpret_cast<const bf16x8*>(qp + 32);
    KSTAGE(0, 0);
#pragma unroll
    for (int c = 0; c < 8; ++c) {
      if (c < 7) KSTAGE(c + 1, (c + 1) & 1);
      if (c < 7) { asm volatile("s_waitcnt vmcnt(4)" ::: "memory"); }
      else       { asm volatile("s_waitcnt vmcnt(0)" ::: "memory"); }
      __builtin_amdgcn_sched_barrier(0);
      const short* kl = &Klds[(c & 1) * 8192];
#pragma unroll
      for (int j = 0; j < 2; ++j) {
        const int lr = 32 * w + 16 * j + c16;
        bf16x8 k0 = *reinterpret_cast<const bf16x8*>(&kl[lr * 64 + 8 * (g ^ sw)]);
        bf16x8 k1 = *reinterpret_cast<const bf16x8*>(&kl[lr * 64 + 8 * ((g + 4) ^ sw)]);
        const int tt = c * 2 + j;
        acc[tt] = mfma16(k0, q0, acc[tt]);
        acc[tt] = mfma16(k1, q1, acc[tt]);
      }
    }
  }

  // prefetch kreg chunk 0 (tile-1 staging) and vreg chunk 0
  bf16x8 kreg[4], vreg[4];
#pragma unroll
  for (int i = 0; i < 4; ++i)
    kreg[i] = *reinterpret_cast<const bf16x8*>(
        kgbase + (size_t)(32 * w + 8 * i + rl) * DIM + 8 * sgl);
#pragma unroll
  for (int dt = 0; dt < 4; ++dt)
    vreg[dt] = *reinterpret_cast<const bf16x8*>(vf + (size_t)((w * 4 + dt) * 512) + lane * 8);

  // ---- softmax tile 0 -> pA ----
  bf16x8 pA[8];
  {
    float m = -1e30f;
#pragma unroll
    for (int tt = 0; tt < 16; ++tt)
#pragma unroll
      for (int e = 0; e < 4; ++e) {
        acc[tt][e] *= 0.125f;
        m = fmaxf(m, acc[tt][e]);
      }
    m = fmaxf(m, __shfl_xor(m, 16));
    m = fmaxf(m, __shfl_xor(m, 32));
    if (g == 0) red[0][w][c16] = m;
    lds_barrier();
    m = fmaxf(fmaxf(red[0][0][c16], red[0][1][c16]),
              fmaxf(red[0][2][c16], red[0][3][c16]));
    float sm = 0.f;
#pragma unroll
    for (int tt = 0; tt < 16; ++tt)
#pragma unroll
      for (int e = 0; e < 4; ++e) {
        const float p = __expf(acc[tt][e] - m);
        acc[tt][e] = p;
        sm += p;
      }
    sm += __shfl_xor(sm, 16);
    sm += __shfl_xor(sm, 32);
    if (g == 0) red[1][w][c16] = sm;
    lds_barrier();
    const float rinv = 1.0f / (red[1][0][c16] + red[1][1][c16] +
                               red[1][2][c16] + red[1][3][c16]);
#pragma unroll
    for (int c = 0; c < 8; ++c) {
      union { bf16x8 v; short sh[8]; } u;
#pragma unroll
      for (int j = 0; j < 2; ++j)
#pragma unroll
        for (int e = 0; e < 4; ++e) {
          u.sh[4 * j + e] = f2bf(acc[2 * c + j][e] * rinv);
          acc[2 * c + j][e] = 0.f;
        }
      pA[c] = u.v;
    }
  }

  f32x4 pacc[4] = {};
  f32x4* red2 = reinterpret_cast<f32x4*>(smem + 32768);   // aliases P32 (free in softmax)

#pragma unroll
  for (int tau = 0; tau < 4; ++tau) {
    const bool qk = (tau < 3);
    // Q for tile tau+1
    bf16x8 qn0, qn1;
    if (qk) {
      const short* qn = Qb + ((size_t)(b * SEQ + rbase + (tau + 1) * 16 + c16)) * DIM +
                        h * HD + 8 * g;
      qn0 = *reinterpret_cast<const bf16x8*>(qn);
      qn1 = *reinterpret_cast<const bf16x8*>(qn + 32);
    }
    float* astore = attnOut + (size_t)b * 8388608 +
                    (size_t)(rbase + tau * 16 + qrow) * 8192 + h * 1024;
#pragma unroll
    for (int c = 0; c < 8; ++c) {
      lds_barrier();
      // region 1: stage K(tau+1,c) + P32(tau,c)
      if (qk) {
#pragma unroll
        for (int i = 0; i < 4; ++i)
          *reinterpret_cast<bf16x8*>(
              &Klds[(c & 1) * 8192 + (32 * w + 8 * i + rl) * 64 + 8 * (sgl ^ rl)]) = kreg[i];
      }
      {
        float* P32w = (c & 1) ? P32b : P32a;
        union { bf16x8 v; short sh[8]; } u; u.v = pA[c];
        f32x4 v0, v1;
#pragma unroll
        for (int e = 0; e < 4; ++e) { v0[e] = bf2f(u.sh[e]); v1[e] = bf2f(u.sh[4 + e]); }
        *reinterpret_cast<f32x4*>(&P32w[c16 * 132 + 32 * w + 4 * g]) = v0;
        *reinterpret_cast<f32x4*>(&P32w[c16 * 132 + 32 * w + 16 + 4 * g]) = v1;
      }
      if (qk) {
#pragma unroll
        for (int i = 0; i < 4; ++i)
          kreg[i] = *reinterpret_cast<const bf16x8*>(
              kgbase + (size_t)((((c + 1) & 7)) * 128 + 32 * w + 8 * i + rl) * DIM + 8 * sgl);
      }
      lds_barrier();
      // region 2: nt stores first (write duty), then QK^T(tau+1), then PV(tau)
      {
        const float* P32r = (c & 1) ? P32b : P32a;
        const f32x4 s0 = *reinterpret_cast<const f32x4*>(&P32r[qrow * 132 + 4 * qs]);
        const f32x4 s1 = *reinterpret_cast<const f32x4*>(&P32r[qrow * 132 + 64 + 4 * qs]);
        __builtin_nontemporal_store(s0, reinterpret_cast<f32x4*>(astore + c * 128 + 4 * qs));
        __builtin_nontemporal_store(s1, reinterpret_cast<f32x4*>(astore + c * 128 + 64 + 4 * qs));
      }
      if (qk) {
        const short* kl = &Klds[(c & 1) * 8192];
#pragma unroll
        for (int j = 0; j < 2; ++j) {
          const int lr = 32 * w + 16 * j + c16;
          bf16x8 k0 = *reinterpret_cast<const bf16x8*>(&kl[lr * 64 + 8 * (g ^ sw)]);
          bf16x8 k1 = *reinterpret_cast<const bf16x8*>(&kl[lr * 64 + 8 * ((g + 4) ^ sw)]);
          const int tt = c * 2 + j;
          acc[tt] = mfma16(k0, qn0, acc[tt]);
          acc[tt] = mfma16(k1, qn1, acc[tt]);
        }
      }
#pragma unroll
      for (int dt = 0; dt < 4; ++dt)
        pacc[dt] = mfma16(pA[c], vreg[dt], pacc[dt]);
      if (!(tau == 3 && c == 7)) {
#pragma unroll
        for (int dt = 0; dt < 4; ++dt)
          vreg[dt] = *reinterpret_cast<const bf16x8*>(
              vf + (size_t)(((((c + 1) & 7) * 4 + w) * 4 + dt) * 512) + lane * 8);
      }
    }

    if (qk) {
      // ---- softmax(tile tau+1) with reduce(tau) riding the barriers ----
      float m = -1e30f;
#pragma unroll
      for (int tt = 0; tt < 16; ++tt)
#pragma unroll
        for (int e = 0; e < 4; ++e) {
          acc[tt][e] *= 0.125f;
          m = fmaxf(m, acc[tt][e]);
        }
      m = fmaxf(m, __shfl_xor(m, 16));
      m = fmaxf(m, __shfl_xor(m, 32));
      if (g == 0) red[0][w][c16] = m;
      lds_barrier();                                     // S1
#pragma unroll
      for (int dt = 0; dt < 4; ++dt) red2[(w * 4 + dt) * 64 + lane] = pacc[dt];
#pragma unroll
      for (int dt = 0; dt < 4; ++dt)
#pragma unroll
        for (int e = 0; e < 4; ++e) pacc[dt][e] = 0.f;
      m = fmaxf(fmaxf(red[0][0][c16], red[0][1][c16]),
                fmaxf(red[0][2][c16], red[0][3][c16]));
      float sm = 0.f;
#pragma unroll
      for (int tt = 0; tt < 16; ++tt)
#pragma unroll
        for (int e = 0; e < 4; ++e) {
          const float pe = __expf(acc[tt][e] - m);
          acc[tt][e] = pe;
          sm += pe;
        }
      sm += __shfl_xor(sm, 16);
      sm += __shfl_xor(sm, 32);
      if (g == 0) red[1][w][c16] = sm;
      lds_barrier();                                     // S2
      {
        const int dt = w;
        f32x4 s = red2[dt * 64 + lane];
#pragma unroll
        for (int w2 = 1; w2 < 4; ++w2) {
          f32x4 o = red2[(w2 * 4 + dt) * 64 + lane];
#pragma unroll
          for (int e = 0; e < 4; ++e) s[e] += o[e];
        }
        short* lrow = Lg + ((size_t)(b * SEQ + rbase + tau * 16 + 4 * g)) * DIM +
                      h * HD + 16 * dt + c16;
#pragma unroll
        for (int e = 0; e < 4; ++e) lrow[(size_t)e * DIM] = f2bf(s[e]);
      }
      const float rinv = 1.0f / (red[1][0][c16] + red[1][1][c16] +
                                 red[1][2][c16] + red[1][3][c16]);
#pragma unroll
      for (int c = 0; c < 8; ++c) {
        union { bf16x8 v; short sh[8]; } u;
#pragma unroll
        for (int j = 0; j < 2; ++j)
#pragma unroll
          for (int e = 0; e < 4; ++e) {
            u.sh[4 * j + e] = f2bf(acc[2 * c + j][e] * rinv);
            acc[2 * c + j][e] = 0.f;
          }
        pA[c] = u.v;
      }
    } else {
      // ---- final reduce + Lg(tile 3) ----
      lds_barrier();
#pragma unroll
      for (int dt = 0; dt < 4; ++dt) red2[(w * 4 + dt) * 64 + lane] = pacc[dt];
      lds_barrier();
      const int dt = w;
      f32x4 s = red2[dt * 64 + lane];
#pragma unroll
      for (int w2 = 1; w2 < 4; ++w2) {
        f32x4 o = red2[(w2 * 4 + dt) * 64 + lane];
#pragma unroll
        for (int e = 0; e < 4; ++e) s[e] += o[e];
      }
      short* lrow = Lg + ((size_t)(b * SEQ + rbase + 48 + 4 * g)) * DIM +
                    h * HD + 16 * dt + c16;
#pragma unroll
      for (int e = 0; e < 4; ++e) lrow[(size_t)e * DIM] = f2bf(s[e]);
    }
  }
}

extern "C" void kernel_launch(void* const* d_in, const int* in_sizes, int n_in,
                              void* d_out, int out_size, void* d_ws, size_t ws_size,
                              hipStream_t stream) {
  const float* x = (const float*)d_in[0];
  const float* Wq = (const float*)d_in[1];
  const float* Wk = (const float*)d_in[2];
  const float* Wv = (const float*)d_in[3];
  const float* Wo = (const float*)d_in[4];
  const float* gamma = (const float*)d_in[5];
  const float* beta = (const float*)d_in[6];
  float* out = (float*)d_out;
  float* attn = out + (size_t)ROWS * DIM;

  char* ws = (char*)d_ws;
  short* xnb = (short*)ws;                                    // 8 MB
  short* WqkvT = (short*)(ws + (size_t)8 * 1024 * 1024);      // 1.5 MB
  short* WoT = WqkvT + 1536 * 512;                            // 0.5 MB
  short* Qb = (short*)(ws + (size_t)10 * 1024 * 1024);        // 8 MB
  short* Kbp = (short*)(ws + (size_t)18 * 1024 * 1024);       // 8 MB
  short* VtF = (short*)(ws + (size_t)26 * 1024 * 1024);       // 8 MB
  short* Lg = (short*)(ws + (size_t)34 * 1024 * 1024);        // 8 MB (ends 42 MB)

  prep_kernel<<<2304, 256, 0, stream>>>(x, gamma, beta, xnb, Wq, Wk, Wv, Wo, WqkvT, WoT);
  gemm_qkv<<<dim3(64, 12), 256, 0, stream>>>(xnb, WqkvT, Qb, Kbp, VtF);
  attn_kernel<<<1024, 256, 0, stream>>>(Qb, Kbp, VtF, attn, Lg);
  gemm_out<<<dim3(64, 4), 256, 0, stream>>>(Lg, WoT, xnb, out);
}

// Round 14
// 119.469 us; speedup vs baseline: 1.2062x; 1.2062x over previous
//
#include <hip/hip_runtime.h>
#include <hip/hip_bf16.h>

typedef __attribute__((ext_vector_type(8))) short bf16x8;
typedef __attribute__((ext_vector_type(4))) short s16x4;
typedef __attribute__((ext_vector_type(4))) float f32x4;

#define DIM 512
#define NH 8
#define HD 64
#define SEQ 1024
#define NB 8
#define ROWS (NB*SEQ)

__device__ __forceinline__ short f2bf(float f) {
  union { float f; unsigned u; } v; v.f = f;
  unsigned r = v.u + 0x7fffu + ((v.u >> 16) & 1u);
  return (short)(r >> 16);
}
__device__ __forceinline__ float bf2f(short s) {
  union { unsigned u; float f; } v; v.u = ((unsigned)(unsigned short)s) << 16;
  return v.f;
}
__device__ __forceinline__ f32x4 mfma16(bf16x8 a, bf16x8 b, f32x4 c) {
  return __builtin_amdgcn_mfma_f32_16x16x32_bf16(a, b, c, 0, 0, 0);
}
__device__ __forceinline__ void gload16(const void* g, void* l) {
  __builtin_amdgcn_global_load_lds(
      (const __attribute__((address_space(1))) unsigned int*)g,
      (__attribute__((address_space(3))) unsigned int*)l, 16, 0, 0);
}
// LDS-only barrier: does NOT drain vmcnt.
__device__ __forceinline__ void lds_barrier() {
  __builtin_amdgcn_sched_barrier(0);
  asm volatile("s_waitcnt lgkmcnt(0)" ::: "memory");
  __builtin_amdgcn_s_barrier();
  __builtin_amdgcn_sched_barrier(0);
}

// ------- fused prep: blocks [0,2048) = LayerNorm; [2048,2304) = weight transpose -------
__global__ __launch_bounds__(256) void prep_kernel(
    const float* __restrict__ x, const float* __restrict__ gamma,
    const float* __restrict__ beta, short* __restrict__ xnb,
    const float* __restrict__ Wq, const float* __restrict__ Wk,
    const float* __restrict__ Wv, const float* __restrict__ Wo,
    short* __restrict__ WqkvT, short* __restrict__ WoT) {
  __shared__ float tl[64 * 65];
  const int t = threadIdx.x;
  if (blockIdx.x < 2048) {
    const int row = blockIdx.x * 4 + (t >> 6);
    const int lane = t & 63;
    const float4* xr = reinterpret_cast<const float4*>(x + (size_t)row * DIM);
    const float4 a = xr[lane * 2], b2 = xr[lane * 2 + 1];
    float s = a.x + a.y + a.z + a.w + b2.x + b2.y + b2.z + b2.w;
    float sq = a.x*a.x + a.y*a.y + a.z*a.z + a.w*a.w +
               b2.x*b2.x + b2.y*b2.y + b2.z*b2.z + b2.w*b2.w;
    for (int off = 1; off < 64; off <<= 1) {
      s += __shfl_xor(s, off);
      sq += __shfl_xor(sq, off);
    }
    const float mean = s * (1.0f / DIM);
    const float var = sq * (1.0f / DIM) - mean * mean;
    const float rs = rsqrtf(var + 1e-5f);
    const float4 ga = reinterpret_cast<const float4*>(gamma)[lane * 2];
    const float4 gb = reinterpret_cast<const float4*>(gamma)[lane * 2 + 1];
    const float4 ba = reinterpret_cast<const float4*>(beta)[lane * 2];
    const float4 bb = reinterpret_cast<const float4*>(beta)[lane * 2 + 1];
    union { bf16x8 v; short sh[8]; } o;
    o.sh[0] = f2bf((a.x - mean) * rs * ga.x + ba.x);
    o.sh[1] = f2bf((a.y - mean) * rs * ga.y + ba.y);
    o.sh[2] = f2bf((a.z - mean) * rs * ga.z + ba.z);
    o.sh[3] = f2bf((a.w - mean) * rs * ga.w + ba.w);
    o.sh[4] = f2bf((b2.x - mean) * rs * gb.x + bb.x);
    o.sh[5] = f2bf((b2.y - mean) * rs * gb.y + bb.y);
    o.sh[6] = f2bf((b2.z - mean) * rs * gb.z + bb.z);
    o.sh[7] = f2bf((b2.w - mean) * rs * gb.w + bb.w);
    *reinterpret_cast<bf16x8*>(xnb + (size_t)row * DIM + lane * 8) = o.v;
  } else {
    const int bb = blockIdx.x - 2048;
    const int y = bb >> 6;
    const float* W = (y == 0) ? Wq : (y == 1) ? Wk : (y == 2) ? Wv : Wo;
    const int tile = bb & 63;
    const int k0 = (tile >> 3) * 64, n0 = (tile & 7) * 64;
#pragma unroll
    for (int i = 0; i < 16; ++i) {
      const int idx = i * 256 + t;
      const int k = idx >> 6, n = idx & 63;
      tl[n * 65 + k] = W[(size_t)(k0 + k) * 512 + n0 + n];
    }
    __syncthreads();
#pragma unroll
    for (int i = 0; i < 16; ++i) {
      const int idx = i * 256 + t;
      const int n = idx >> 6, k = idx & 63;
      const short v = f2bf(tl[n * 65 + k]);
      if (y < 3) WqkvT[(size_t)(y * 512 + n0 + n) * 512 + k0 + k] = v;
      else       WoT[(size_t)(n0 + n) * 512 + k0 + k] = v;
    }
  }
}

// ---------------- 128x128 GEMM mainloop, BK=64, 8-seg XOR swizzle ----------------
#define GEMM64_MAIN(A_, BT_, m0_, n0_)                                        \
  f32x4 acc[4][4] = {};                                                       \
  {                                                                           \
    const int srow = 8 * w + (lane >> 3);                                     \
    const int sseg = lane & 7;                                                \
    for (int kb = 0; kb < 512; kb += 64) {                                    \
      __syncthreads();                                                        \
      _Pragma("unroll")                                                       \
      for (int p = 0; p < 4; ++p) {                                           \
        const int r = 32 * p + srow;                                          \
        const int gs = 8 * (sseg ^ (r & 7));                                  \
        gload16(A_ + (size_t)(m0_ + r) * 512 + kb + gs,                       \
                &As[(32 * p + 8 * w) * 64]);                                  \
        gload16(BT_ + (size_t)(n0_ + r) * 512 + kb + gs,                      \
                &Bs[(32 * p + 8 * w) * 64]);                                  \
      }                                                                       \
      __syncthreads();                                                        \
      _Pragma("unroll")                                                       \
      for (int half = 0; half < 2; ++half) {                                  \
        bf16x8 af[4], bfr[4];                                                 \
        _Pragma("unroll")                                                     \
        for (int i = 0; i < 4; ++i) {                                         \
          const int ra = 64 * wr + 16 * i + c16;                              \
          af[i] = *reinterpret_cast<const bf16x8*>(                           \
              &As[ra * 64 + 8 * ((4 * half + g) ^ (ra & 7))]);                \
          const int rb = 64 * wc + 16 * i + c16;                              \
          bfr[i] = *reinterpret_cast<const bf16x8*>(                          \
              &Bs[rb * 64 + 8 * ((4 * half + g) ^ (rb & 7))]);                \
        }                                                                     \
        _Pragma("unroll")                                                     \
        for (int i = 0; i < 4; ++i)                                           \
          _Pragma("unroll")                                                   \
          for (int j = 0; j < 4; ++j)                                         \
            acc[i][j] = mfma16(af[i], bfr[j], acc[i][j]);                     \
      }                                                                       \
    }                                                                         \
  }

// QKV GEMM. V written in MFMA-fragment order MATCHING pa's slot map:
// slot (g,i) <-> k-offset 16*(i>>2) + 4*g + (i&3)
__global__ __launch_bounds__(256) void gemm_qkv(const short* __restrict__ A,
    const short* __restrict__ BT, short* __restrict__ Qo,
    short* __restrict__ Ko, short* __restrict__ VtF) {
  __shared__ short As[128 * 64];
  __shared__ short Bs[128 * 64];
  const int m0 = blockIdx.x * 128, n0 = blockIdx.y * 128;
  const int t = threadIdx.x, w = t >> 6, lane = t & 63, g = lane >> 4, c16 = lane & 15;
  const int wr = w >> 1, wc = w & 1;
  GEMM64_MAIN(A, BT, m0, n0)
  const int z = n0 >> 9;
  const int nl = n0 & 511;
  if (z < 2) {
    short* O = (z == 0) ? Qo : Ko;
#pragma unroll
    for (int i = 0; i < 4; ++i)
#pragma unroll
      for (int j = 0; j < 4; ++j) {
        const int row0 = m0 + 64 * wr + 16 * i + 4 * g;
        const int col = nl + 64 * wc + 16 * j + c16;
#pragma unroll
        for (int e = 0; e < 4; ++e)
          O[(size_t)(row0 + e) * 512 + col] = f2bf(acc[i][j][e]);
      }
  } else {
#pragma unroll
    for (int i = 0; i < 4; ++i)
#pragma unroll
      for (int j = 0; j < 4; ++j) {
        const int row0 = m0 + 64 * wr + 16 * i + 4 * g;   // e=0 base
        const int col = nl + 64 * wc + 16 * j + c16;
        const int bb = row0 >> 10, ss0 = row0 & 1023, hh = col >> 6, dd = col & 63;
        const int cch = ss0 >> 7, kk = ss0 & 127;
        const int w2 = kk >> 5;
        const int g2 = (kk >> 2) & 3;                     // matched slot order
        const int ee0 = 4 * ((kk >> 4) & 1) + (kk & 3);   // ee0 in {0,4}
        const int dt2 = dd >> 4, c162 = dd & 15;
        s16x4 pv;
#pragma unroll
        for (int e = 0; e < 4; ++e) pv[e] = f2bf(acc[i][j][e]);
        *reinterpret_cast<s16x4*>(
            &VtF[((size_t)((((bb * NH + hh) * 8 + cch) * 4 + w2) * 4 + dt2) << 9) +
                 (g2 * 16 + c162) * 8 + ee0]) = pv;
      }
  }
}

__global__ __launch_bounds__(256) void gemm_out(const short* __restrict__ A,
    const short* __restrict__ BT, const short* __restrict__ xnb,
    float* __restrict__ out) {
  __shared__ short As[128 * 64];
  __shared__ short Bs[128 * 64];
  const int m0 = blockIdx.x * 128, n0 = blockIdx.y * 128;
  const int t = threadIdx.x, w = t >> 6, lane = t & 63, g = lane >> 4, c16 = lane & 15;
  const int wr = w >> 1, wc = w & 1;
  GEMM64_MAIN(A, BT, m0, n0)
#pragma unroll
  for (int i = 0; i < 4; ++i)
#pragma unroll
    for (int j = 0; j < 4; ++j)
#pragma unroll
      for (int e = 0; e < 4; ++e) {
        const int row = m0 + 64 * wr + 16 * i + 4 * g + e;
        const int col = n0 + 64 * wc + 16 * j + c16;
        const size_t idx = (size_t)row * 512 + col;
        out[idx] = acc[i][j][e] + bf2f(xnb[idx]);
      }
}

// ------- pipelined attn (r9 schedule; 40KB LDS for 4 blocks/CU; exact 2 generations) -------
// Single P32 buffer [16][128] with XOR col-swizzle (col ^= 4*(row&7)) on write+read;
// softmax red arrays aliased into the P32 region (temporally disjoint).
__global__ __launch_bounds__(256, 2) void attn_kernel(
    const short* __restrict__ Qb, const short* __restrict__ Kb,
    const short* __restrict__ VtF, float* __restrict__ attnOut,
    short* __restrict__ Lg) {
  const int bid = blockIdx.x;                 // 2048
  const int rb = (bid >> 3) & 31;             // 32-row block
  const int inst = (bid & 7) * 8 + (bid >> 8);
  const int b = inst >> 3, h = inst & 7;
  const int t = threadIdx.x;
  const int w = t >> 6, lane = t & 63, g = lane >> 4, c16 = lane & 15;
  const int rl = lane >> 3, sgl = lane & 7;

  __shared__ __align__(16) char smem[40960];
  short* Klds = (short*)smem;                  // [2][128*64] = 32 KB
  float* P32 = (float*)(smem + 32768);         // [16][128] swizzled = 8 KB
  float* redm = P32;                           // alias: 64 floats (softmax max)
  float* reds = P32 + 64;                      // alias: 64 floats (softmax sum)

  const short* qpa = Qb + ((size_t)(b * SEQ + rb * 32 + c16)) * DIM + h * HD + 8 * g;
  const bf16x8 qa0 = *reinterpret_cast<const bf16x8*>(qpa);
  const bf16x8 qa1 = *reinterpret_cast<const bf16x8*>(qpa + 32);
  const bf16x8 qB0 = *reinterpret_cast<const bf16x8*>(qpa + 16 * DIM);
  const bf16x8 qB1 = *reinterpret_cast<const bf16x8*>(qpa + 16 * DIM + 32);

  const short* kgbase = Kb + ((size_t)b * SEQ) * DIM + h * HD;
  const int swz = 8 * (sgl ^ rl);
  const int sw = c16 & 7;
  const int sw32 = 4 * (c16 & 7);              // P32 write swizzle (row = c16)

#define KSTAGE(c_, buf_)                                                       \
  do {                                                                         \
    __builtin_amdgcn_sched_barrier(0);                                         \
    _Pragma("unroll") for (int i_ = 0; i_ < 4; ++i_) {                         \
      gload16(kgbase + (size_t)((c_) * 128 + 32 * w + 8 * i_ + rl) * DIM + swz,\
              &Klds[(buf_) * 8192 + (32 * w + 8 * i_) * 64]);                  \
    }                                                                          \
  } while (0)

  // ---- phase 1: QK^T tile A ----
  KSTAGE(0, 0);
  f32x4 acc[16] = {};
#pragma unroll
  for (int c = 0; c < 8; ++c) {
    if (c < 7) KSTAGE(c + 1, (c + 1) & 1);
    if (c < 7) { asm volatile("s_waitcnt vmcnt(4)" ::: "memory"); }
    else       { asm volatile("s_waitcnt vmcnt(0)" ::: "memory"); }
    __builtin_amdgcn_sched_barrier(0);
    const short* kl = &Klds[(c & 1) * 8192];
#pragma unroll
    for (int j = 0; j < 2; ++j) {
      const int lr = 32 * w + 16 * j + c16;
      bf16x8 k0 = *reinterpret_cast<const bf16x8*>(&kl[lr * 64 + 8 * (g ^ sw)]);
      bf16x8 k1 = *reinterpret_cast<const bf16x8*>(&kl[lr * 64 + 8 * ((g + 4) ^ sw)]);
      const int tt = c * 2 + j;
      acc[tt] = mfma16(k0, qa0, acc[tt]);
      acc[tt] = mfma16(k1, qa1, acc[tt]);
    }
  }

  // prefetch V frags (chunk 0) and K regs (tile-B staging chunk 0)
  const short* vf = VtF + (size_t)inst * 65536;
  bf16x8 vreg[4];
#pragma unroll
  for (int dt = 0; dt < 4; ++dt)
    vreg[dt] = *reinterpret_cast<const bf16x8*>(vf + (size_t)((w * 4 + dt) * 512) + lane * 8);
  bf16x8 kreg[4];
#pragma unroll
  for (int i = 0; i < 4; ++i)
    kreg[i] = *reinterpret_cast<const bf16x8*>(
        kgbase + (size_t)(32 * w + 8 * i + rl) * DIM + 8 * sgl);

  // ---- softmax A (red arrays live in P32 region; P32 untouched so far) ----
  float m = -1e30f;
#pragma unroll
  for (int tt = 0; tt < 16; ++tt)
#pragma unroll
    for (int e = 0; e < 4; ++e) {
      acc[tt][e] *= 0.125f;
      m = fmaxf(m, acc[tt][e]);
    }
  m = fmaxf(m, __shfl_xor(m, 16));
  m = fmaxf(m, __shfl_xor(m, 32));
  if (g == 0) redm[w * 16 + c16] = m;
  lds_barrier();
  m = fmaxf(fmaxf(redm[c16], redm[16 + c16]),
            fmaxf(redm[32 + c16], redm[48 + c16]));
  float sm = 0.f;
#pragma unroll
  for (int tt = 0; tt < 16; ++tt)
#pragma unroll
    for (int e = 0; e < 4; ++e) {
      const float p = __expf(acc[tt][e] - m);
      acc[tt][e] = p;
      sm += p;
    }
  sm += __shfl_xor(sm, 16);
  sm += __shfl_xor(sm, 32);
  if (g == 0) reds[w * 16 + c16] = sm;
  lds_barrier();
  const float rinvA = 1.0f / (reds[c16] + reds[16 + c16] +
                              reds[32 + c16] + reds[48 + c16]);

  // pack normalized P(A) to bf16 regs; free acc for tile B
  bf16x8 pA[8];
#pragma unroll
  for (int c = 0; c < 8; ++c) {
    union { bf16x8 v; short sh[8]; } u;
#pragma unroll
    for (int j = 0; j < 2; ++j)
#pragma unroll
      for (int e = 0; e < 4; ++e)
        u.sh[4 * j + e] = f2bf(acc[2 * c + j][e] * rinvA);
    pA[c] = u.v;
  }
#pragma unroll
  for (int tt = 0; tt < 16; ++tt)
#pragma unroll
    for (int e = 0; e < 4; ++e) acc[tt][e] = 0.f;

  // ---- phase 2: QK^T(B) || stores(A) || PV(A) ----
  f32x4 paccA[4] = {};
  const int qrow = t >> 4, qs = t & 15;
  const int rsw = 4 * (qrow & 7);              // P32 read swizzle (row = qrow)
  float* astore = attnOut + (size_t)b * 8388608 +
                  (size_t)(rb * 32 + qrow) * 8192 + h * 1024;
#pragma unroll
  for (int c = 0; c < 8; ++c) {
    lds_barrier();
    // region 1: stage K(B,c) + P32(A,c)
#pragma unroll
    for (int i = 0; i < 4; ++i)
      *reinterpret_cast<bf16x8*>(
          &Klds[(c & 1) * 8192 + (32 * w + 8 * i + rl) * 64 + 8 * (sgl ^ rl)]) = kreg[i];
    {
      union { bf16x8 v; short sh[8]; } u; u.v = pA[c];
      f32x4 v0, v1;
#pragma unroll
      for (int e = 0; e < 4; ++e) { v0[e] = bf2f(u.sh[e]); v1[e] = bf2f(u.sh[4 + e]); }
      *reinterpret_cast<f32x4*>(&P32[c16 * 128 + ((32 * w + 4 * g) ^ sw32)]) = v0;
      *reinterpret_cast<f32x4*>(&P32[c16 * 128 + ((32 * w + 16 + 4 * g) ^ sw32)]) = v1;
    }
    if (c < 7) {
#pragma unroll
      for (int i = 0; i < 4; ++i)
        kreg[i] = *reinterpret_cast<const bf16x8*>(
            kgbase + (size_t)((c + 1) * 128 + 32 * w + 8 * i + rl) * DIM + 8 * sgl);
    }
    lds_barrier();
    // region 2: nt stores first (write duty), then QK^T(B), then PV(A)
    {
      const f32x4 s0 = *reinterpret_cast<const f32x4*>(&P32[qrow * 128 + ((4 * qs) ^ rsw)]);
      const f32x4 s1 = *reinterpret_cast<const f32x4*>(&P32[qrow * 128 + ((64 + 4 * qs) ^ rsw)]);
      __builtin_nontemporal_store(s0, reinterpret_cast<f32x4*>(astore + c * 128 + 4 * qs));
      __builtin_nontemporal_store(s1, reinterpret_cast<f32x4*>(astore + c * 128 + 64 + 4 * qs));
    }
    const short* kl = &Klds[(c & 1) * 8192];
#pragma unroll
    for (int j = 0; j < 2; ++j) {
      const int lr = 32 * w + 16 * j + c16;
      bf16x8 k0 = *reinterpret_cast<const bf16x8*>(&kl[lr * 64 + 8 * (g ^ sw)]);
      bf16x8 k1 = *reinterpret_cast<const bf16x8*>(&kl[lr * 64 + 8 * ((g + 4) ^ sw)]);
      const int tt = c * 2 + j;
      acc[tt] = mfma16(k0, qB0, acc[tt]);
      acc[tt] = mfma16(k1, qB1, acc[tt]);
    }
#pragma unroll
    for (int dt = 0; dt < 4; ++dt)
      paccA[dt] = mfma16(pA[c], vreg[dt], paccA[dt]);
    if (c < 7) {
#pragma unroll
      for (int dt = 0; dt < 4; ++dt)
        vreg[dt] = *reinterpret_cast<const bf16x8*>(
            vf + (size_t)((((c + 1) * 4 + w) * 4 + dt) * 512) + lane * 8);
    }
  }

  // prefetch V frags chunk 0 for phase 3
#pragma unroll
  for (int dt = 0; dt < 4; ++dt)
    vreg[dt] = *reinterpret_cast<const bf16x8*>(vf + (size_t)((w * 4 + dt) * 512) + lane * 8);

  // ---- softmax B (fence last P32 reads before clobbering red alias) ----
  float mB = -1e30f;
#pragma unroll
  for (int tt = 0; tt < 16; ++tt)
#pragma unroll
    for (int e = 0; e < 4; ++e) {
      acc[tt][e] *= 0.125f;
      mB = fmaxf(mB, acc[tt][e]);
    }
  mB = fmaxf(mB, __shfl_xor(mB, 16));
  mB = fmaxf(mB, __shfl_xor(mB, 32));
  lds_barrier();                               // all P32 chunk-7 reads complete
  if (g == 0) redm[w * 16 + c16] = mB;
  lds_barrier();
  mB = fmaxf(fmaxf(redm[c16], redm[16 + c16]),
             fmaxf(redm[32 + c16], redm[48 + c16]));
  float smB = 0.f;
#pragma unroll
  for (int tt = 0; tt < 16; ++tt)
#pragma unroll
    for (int e = 0; e < 4; ++e) {
      const float p = __expf(acc[tt][e] - mB);
      acc[tt][e] = p;
      smB += p;
    }
  smB += __shfl_xor(smB, 16);
  smB += __shfl_xor(smB, 32);
  if (g == 0) reds[w * 16 + c16] = smB;
  lds_barrier();
  const float rinvB = 1.0f / (reds[c16] + reds[16 + c16] +
                              reds[32 + c16] + reds[48 + c16]);
  bf16x8 pB[8];
#pragma unroll
  for (int c = 0; c < 8; ++c) {
    union { bf16x8 v; short sh[8]; } u;
#pragma unroll
    for (int j = 0; j < 2; ++j)
#pragma unroll
      for (int e = 0; e < 4; ++e)
        u.sh[4 * j + e] = f2bf(acc[2 * c + j][e] * rinvB);
    pB[c] = u.v;
  }

  // ---- phase 3: stores(B) + PV(B) ----
  f32x4 paccB[4] = {};
  float* astoreB = astore + 16 * 8192;
#pragma unroll
  for (int c = 0; c < 8; ++c) {
    lds_barrier();
    {
      union { bf16x8 v; short sh[8]; } u; u.v = pB[c];
      f32x4 v0, v1;
#pragma unroll
      for (int e = 0; e < 4; ++e) { v0[e] = bf2f(u.sh[e]); v1[e] = bf2f(u.sh[4 + e]); }
      *reinterpret_cast<f32x4*>(&P32[c16 * 128 + ((32 * w + 4 * g) ^ sw32)]) = v0;
      *reinterpret_cast<f32x4*>(&P32[c16 * 128 + ((32 * w + 16 + 4 * g) ^ sw32)]) = v1;
    }
    lds_barrier();
    {
      const f32x4 s0 = *reinterpret_cast<const f32x4*>(&P32[qrow * 128 + ((4 * qs) ^ rsw)]);
      const f32x4 s1 = *reinterpret_cast<const f32x4*>(&P32[qrow * 128 + ((64 + 4 * qs) ^ rsw)]);
      __builtin_nontemporal_store(s0, reinterpret_cast<f32x4*>(astoreB + c * 128 + 4 * qs));
      __builtin_nontemporal_store(s1, reinterpret_cast<f32x4*>(astoreB + c * 128 + 64 + 4 * qs));
    }
#pragma unroll
    for (int dt = 0; dt < 4; ++dt)
      paccB[dt] = mfma16(pB[c], vreg[dt], paccB[dt]);
    if (c < 7) {
#pragma unroll
      for (int dt = 0; dt < 4; ++dt)
        vreg[dt] = *reinterpret_cast<const bf16x8*>(
            vf + (size_t)((((c + 1) * 4 + w) * 4 + dt) * 512) + lane * 8);
    }
  }

  // ---- epilogue: cross-wave reduce (red2 aliases Klds) + Lg writes ----
  lds_barrier();
  f32x4* red2 = reinterpret_cast<f32x4*>(smem);
#pragma unroll
  for (int dt = 0; dt < 4; ++dt) red2[(w * 4 + dt) * 64 + lane] = paccA[dt];
  lds_barrier();
  {
    const int dt = w;
    f32x4 s = red2[dt * 64 + lane];
#pragma unroll
    for (int w2 = 1; w2 < 4; ++w2) {
      f32x4 o = red2[(w2 * 4 + dt) * 64 + lane];
#pragma unroll
      for (int e = 0; e < 4; ++e) s[e] += o[e];
    }
    short* lrow = Lg + ((size_t)(b * SEQ + rb * 32 + 4 * g)) * DIM + h * HD + 16 * dt + c16;
#pragma unroll
    for (int e = 0; e < 4; ++e) lrow[(size_t)e * DIM] = f2bf(s[e]);
  }
  lds_barrier();
#pragma unroll
  for (int dt = 0; dt < 4; ++dt) red2[(w * 4 + dt) * 64 + lane] = paccB[dt];
  lds_barrier();
  {
    const int dt = w;
    f32x4 s = red2[dt * 64 + lane];
#pragma unroll
    for (int w2 = 1; w2 < 4; ++w2) {
      f32x4 o = red2[(w2 * 4 + dt) * 64 + lane];
#pragma unroll
      for (int e = 0; e < 4; ++e) s[e] += o[e];
    }
    short* lrow = Lg + ((size_t)(b * SEQ + rb * 32 + 16 + 4 * g)) * DIM + h * HD + 16 * dt + c16;
#pragma unroll
    for (int e = 0; e < 4; ++e) lrow[(size_t)e * DIM] = f2bf(s[e]);
  }
}

extern "C" void kernel_launch(void* const* d_in, const int* in_sizes, int n_in,
                              void* d_out, int out_size, void* d_ws, size_t ws_size,
                              hipStream_t stream) {
  const float* x = (const float*)d_in[0];
  const float* Wq = (const float*)d_in[1];
  const float* Wk = (const float*)d_in[2];
  const float* Wv = (const float*)d_in[3];
  const float* Wo = (const float*)d_in[4];
  const float* gamma = (const float*)d_in[5];
  const float* beta = (const float*)d_in[6];
  float* out = (float*)d_out;
  float* attn = out + (size_t)ROWS * DIM;

  char* ws = (char*)d_ws;
  short* xnb = (short*)ws;                                    // 8 MB
  short* WqkvT = (short*)(ws + (size_t)8 * 1024 * 1024);      // 1.5 MB
  short* WoT = WqkvT + 1536 * 512;                            // 0.5 MB
  short* Qb = (short*)(ws + (size_t)10 * 1024 * 1024);        // 8 MB
  short* Kbp = (short*)(ws + (size_t)18 * 1024 * 1024);       // 8 MB
  short* VtF = (short*)(ws + (size_t)26 * 1024 * 1024);       // 8 MB
  short* Lg = (short*)(ws + (size_t)34 * 1024 * 1024);        // 8 MB (ends 42 MB)

  prep_kernel<<<2304, 256, 0, stream>>>(x, gamma, beta, xnb, Wq, Wk, Wv, Wo, WqkvT, WoT);
  gemm_qkv<<<dim3(64, 12), 256, 0, stream>>>(xnb, WqkvT, Qb, Kbp, VtF);
  attn_kernel<<<2048, 256, 0, stream>>>(Qb, Kbp, VtF, attn, Lg);
  gemm_out<<<dim3(64, 4), 256, 0, stream>>>(Lg, WoT, xnb, out);
}